// Round 1
// baseline (2121.996 us; speedup 1.0000x reference)
//
#include <hip/hip_runtime.h>
#include <math.h>

typedef unsigned short u16;
typedef float v4f __attribute__((ext_vector_type(4)));
typedef short v8s __attribute__((ext_vector_type(8)));

// ---------- helpers ----------
__device__ __forceinline__ u16 f2bf(float f) {
  union { float f; unsigned u; } c; c.f = f;
  unsigned u = c.u;
  u += 0x7fff + ((u >> 16) & 1);   // RNE
  return (u16)(u >> 16);
}

// window-row r (win*64+n, shifted frame) -> natural token index.
// shifted coord s maps to natural (s+2)%S for both the LN1 gather and the
// output scatter (roll -2 before partition, roll +2 after reverse).
__device__ __forceinline__ int row_to_token(int r) {
  int win = r >> 6, n = r & 63;
  int b = (win >= 784) ? 1 : 0;
  int wrem = win - b * 784;
  int wd = wrem / 196;
  int r2 = wrem - wd * 196;
  int wh = r2 / 14;
  int ww = r2 - wh * 14;
  int d = wd * 4 + (n >> 4);
  int h = wh * 4 + ((n >> 2) & 3);
  int w = ww * 4 + (n & 3);
  d = (d + 2) & 15;
  h += 2; if (h >= 56) h -= 56;
  w += 2; if (w >= 56) w -= 56;
  return ((b * 16 + d) * 56 + h) * 56 + w;
}

// region label for shift-mask; nonzero only in boundary windows
__device__ __forceinline__ int region_label(int n, int bd, int bh, int bw) {
  int ld = bd ? (((n >> 4) >= 2) ? 2 : 1) : 0;
  int lh = bh ? ((((n >> 2) & 3) >= 2) ? 2 : 1) : 0;
  int lw = bw ? (((n & 3) >= 2) ? 2 : 1) : 0;
  return ld * 9 + lh * 3 + lw;
}

// ---------- tiny prep kernels ----------
__global__ __launch_bounds__(256) void cvt_weights(const float* __restrict__ a, const float* __restrict__ b,
                                                   const float* __restrict__ c, const float* __restrict__ d,
                                                   u16* __restrict__ dst) {
  int i = blockIdx.x * 256 + threadIdx.x;   // grid covers exactly 1769472
  float v;
  if (i < 442368)       v = a[i];
  else if (i < 589824)  v = b[i - 442368];
  else if (i < 1179648) v = c[i - 589824];
  else                  v = d[i - 1179648];
  dst[i] = f2bf(v);
}

__global__ __launch_bounds__(256) void bias_kernel(const float* __restrict__ rpb, float* __restrict__ biasb) {
  int i = blockIdx.x * 256 + threadIdx.x;   // 49152 = 12*64*64, layout [h][n][m]
  int h = i >> 12, n = (i >> 6) & 63, m = i & 63;
  int dd = (n >> 4) - (m >> 4) + 3;
  int dh = ((n >> 2) & 3) - ((m >> 2) & 3) + 3;
  int dw = (n & 3) - (m & 3) + 3;
  biasb[i] = rpb[(dd * 49 + dh * 7 + dw) * 12 + h];
}

// ---------- LayerNorm (one wave per token row) ----------
template<bool MAP>
__global__ __launch_bounds__(256) void ln_kernel(const float* __restrict__ x, const float* __restrict__ g,
                                                 const float* __restrict__ bta, u16* __restrict__ out) {
  int wid = threadIdx.x >> 6, lane = threadIdx.x & 63;
  int r = blockIdx.x * 4 + wid;
  int t = MAP ? row_to_token(r) : r;
  const float* src = x + (size_t)t * 384;
  float v[6]; float s = 0.f;
#pragma unroll
  for (int i = 0; i < 6; i++) { v[i] = src[lane + i * 64]; s += v[i]; }
#pragma unroll
  for (int off = 1; off < 64; off <<= 1) s += __shfl_xor(s, off);
  float mu = s * (1.f / 384.f);
  float vs = 0.f;
#pragma unroll
  for (int i = 0; i < 6; i++) { float d = v[i] - mu; vs += d * d; }
#pragma unroll
  for (int off = 1; off < 64; off <<= 1) vs += __shfl_xor(vs, off);
  float rstd = 1.f / sqrtf(vs * (1.f / 384.f) + 1e-5f);
  u16* dst = out + (size_t)r * 384;
#pragma unroll
  for (int i = 0; i < 6; i++) {
    int c = lane + i * 64;
    dst[c] = f2bf((v[i] - mu) * rstd * g[c] + bta[c]);
  }
}

// ---------- GEMM: 128x128 tile, BK=32, 4 waves, 16x16x32 bf16 MFMA ----------
// EPI: 0=qkv(bias->bf16)  1=proj(bias + scatter + shortcut -> f32 d_out)
//      2=fc1(bias+gelu->bf16)  3=fc2(bias, += d_out f32)
template<int EPI>
__global__ __launch_bounds__(256) void gemm_bf16(const u16* __restrict__ A, const u16* __restrict__ Bw,
                                                 const float* __restrict__ bias, int M, int N, int K,
                                                 u16* __restrict__ out_bf, float* __restrict__ out_f,
                                                 const float* __restrict__ resid) {
  __shared__ u16 As[128][40];   // [m][k], +8 pad keeps 16B align, ~2-way banks
  __shared__ u16 Bs[128][40];   // [n][k]
  const int tid = threadIdx.x;
  const int m0 = blockIdx.x * 128;
  const int n0 = blockIdx.y * 128;
  const int wid = tid >> 6, lane = tid & 63;
  const int wm = (wid >> 1) * 64, wn = (wid & 1) * 64;
  const int l15 = lane & 15, q4 = lane >> 4;
  v4f acc[4][4];
#pragma unroll
  for (int i = 0; i < 4; i++)
#pragma unroll
    for (int j = 0; j < 4; j++) acc[i][j] = (v4f){0.f, 0.f, 0.f, 0.f};

  const int arow = tid >> 2, akc = (tid & 3) * 8;
  const int bkr = tid >> 4, bnc = (tid & 15) * 8;

  for (int k0 = 0; k0 < K; k0 += 32) {
#pragma unroll
    for (int i = 0; i < 2; i++) {           // A tile 128x32
      int r = arow + i * 64;
      float4 ld = *(const float4*)(A + (size_t)(m0 + r) * K + k0 + akc);
      *(float4*)&As[r][akc] = ld;
    }
#pragma unroll
    for (int i = 0; i < 2; i++) {           // B tile 32x128, transpose into [n][k]
      int kk = bkr + i * 16;
      float4 ld = *(const float4*)(Bw + (size_t)(k0 + kk) * N + n0 + bnc);
      const u16* t = (const u16*)&ld;
#pragma unroll
      for (int j = 0; j < 8; j++) Bs[bnc + j][kk] = t[j];
    }
    __syncthreads();
    v8s afr[4], bfr[4];
#pragma unroll
    for (int tm = 0; tm < 4; tm++) afr[tm] = *(const v8s*)&As[wm + tm * 16 + l15][q4 * 8];
#pragma unroll
    for (int tn = 0; tn < 4; tn++) bfr[tn] = *(const v8s*)&Bs[wn + tn * 16 + l15][q4 * 8];
#pragma unroll
    for (int tm = 0; tm < 4; tm++)
#pragma unroll
      for (int tn = 0; tn < 4; tn++)
        acc[tm][tn] = __builtin_amdgcn_mfma_f32_16x16x32_bf16(afr[tm], bfr[tn], acc[tm][tn], 0, 0, 0);
    __syncthreads();
  }

#pragma unroll
  for (int tm = 0; tm < 4; tm++) {
#pragma unroll
    for (int tn = 0; tn < 4; tn++) {
      const int gcol = n0 + wn + tn * 16 + l15;
      const float bb = bias[gcol];
#pragma unroll
      for (int r = 0; r < 4; r++) {
        const int grow = m0 + wm + tm * 16 + q4 * 4 + r;
        float val = acc[tm][tn][r] + bb;
        if constexpr (EPI == 0) {
          out_bf[(size_t)grow * N + gcol] = f2bf(val);
        } else if constexpr (EPI == 2) {
          val = 0.5f * val * (1.f + erff(val * 0.70710678118654752f));
          out_bf[(size_t)grow * N + gcol] = f2bf(val);
        } else if constexpr (EPI == 1) {
          int t_ = row_to_token(grow);
          out_f[(size_t)t_ * 384 + gcol] = resid[(size_t)t_ * 384 + gcol] + val;
        } else {
          out_f[(size_t)grow * 384 + gcol] += val;
        }
      }
    }
  }
}

// ---------- attention: one wave per (window, head) ----------
__global__ __launch_bounds__(256) void attn_kernel(const u16* __restrict__ qkv, const float* __restrict__ biasb,
                                                   u16* __restrict__ outb) {
  __shared__ u16 P[4][64][72];              // per-wave P tile, bf16, padded
  int wid = threadIdx.x >> 6, lane = threadIdx.x & 63;
  int g = blockIdx.x * 4 + wid;
  int win = g / 12, head = g - win * 12;
  int l15 = lane & 15, q4 = lane >> 4;
  const u16* base = qkv + (size_t)win * 64 * 1152;
  const u16* qp = base + head * 32;
  const u16* kp = base + 384 + head * 32;
  const u16* vp = base + 768 + head * 32;

  v8s a[4], kb[4];
#pragma unroll
  for (int tm = 0; tm < 4; tm++) a[tm] = *(const v8s*)(qp + (size_t)(tm * 16 + l15) * 1152 + q4 * 8);
#pragma unroll
  for (int tn = 0; tn < 4; tn++) kb[tn] = *(const v8s*)(kp + (size_t)(tn * 16 + l15) * 1152 + q4 * 8);
  v4f acc[4][4];
#pragma unroll
  for (int i = 0; i < 4; i++)
#pragma unroll
    for (int j = 0; j < 4; j++) acc[i][j] = (v4f){0.f, 0.f, 0.f, 0.f};
#pragma unroll
  for (int tm = 0; tm < 4; tm++)
#pragma unroll
    for (int tn = 0; tn < 4; tn++)
      acc[tm][tn] = __builtin_amdgcn_mfma_f32_16x16x32_bf16(a[tm], kb[tn], acc[tm][tn], 0, 0, 0);

  // scale + rel-pos bias + shift mask + softmax (rows in C-layout: n = tm*16+q4*4+r)
  int wrem = win % 784;
  int wd = wrem / 196, r2 = wrem % 196, wh = r2 / 14, ww = r2 % 14;
  int bd = (wd == 3), bh = (wh == 13), bw = (ww == 13);
  const float* bptr = biasb + head * 4096;
  int mlab[4];
#pragma unroll
  for (int tn = 0; tn < 4; tn++) mlab[tn] = region_label(tn * 16 + l15, bd, bh, bw);

#pragma unroll
  for (int tm = 0; tm < 4; tm++) {
#pragma unroll
    for (int r = 0; r < 4; r++) {
      int n = tm * 16 + q4 * 4 + r;
      int nlab = region_label(n, bd, bh, bw);
      float sv[4];
      float mx = -1e30f;
#pragma unroll
      for (int tn = 0; tn < 4; tn++) {
        int m = tn * 16 + l15;
        float s = acc[tm][tn][r] * 0.17677669529663687f + bptr[n * 64 + m];
        if (mlab[tn] != nlab) s -= 100.f;
        sv[tn] = s;
        mx = fmaxf(mx, s);
      }
#pragma unroll
      for (int off = 1; off < 16; off <<= 1) mx = fmaxf(mx, __shfl_xor(mx, off));
      float sum = 0.f;
#pragma unroll
      for (int tn = 0; tn < 4; tn++) { float e = __expf(sv[tn] - mx); sv[tn] = e; sum += e; }
#pragma unroll
      for (int off = 1; off < 16; off <<= 1) sum += __shfl_xor(sum, off);
      float inv = 1.f / sum;
#pragma unroll
      for (int tn = 0; tn < 4; tn++) P[wid][n][tn * 16 + l15] = f2bf(sv[tn] * inv);
    }
  }
  __syncthreads();   // C-layout -> A-layout via LDS (verified m120 pattern)

  v4f o[4][2];
#pragma unroll
  for (int i = 0; i < 4; i++) { o[i][0] = (v4f){0.f,0.f,0.f,0.f}; o[i][1] = (v4f){0.f,0.f,0.f,0.f}; }
#pragma unroll
  for (int kt = 0; kt < 2; kt++) {
    v8s pa[4];
#pragma unroll
    for (int tm = 0; tm < 4; tm++) pa[tm] = *(const v8s*)&P[wid][tm * 16 + l15][kt * 32 + q4 * 8];
#pragma unroll
    for (int tn = 0; tn < 2; tn++) {
      v8s vb;
#pragma unroll
      for (int j = 0; j < 8; j++) vb[j] = (short)vp[(size_t)(kt * 32 + q4 * 8 + j) * 1152 + tn * 16 + l15];
#pragma unroll
      for (int tm = 0; tm < 4; tm++)
        o[tm][tn] = __builtin_amdgcn_mfma_f32_16x16x32_bf16(pa[tm], vb, o[tm][tn], 0, 0, 0);
    }
  }
#pragma unroll
  for (int tm = 0; tm < 4; tm++)
#pragma unroll
    for (int tn = 0; tn < 2; tn++)
#pragma unroll
      for (int r = 0; r < 4; r++) {
        int n = tm * 16 + q4 * 4 + r;
        outb[(size_t)(win * 64 + n) * 384 + head * 32 + tn * 16 + l15] = f2bf(o[tm][tn][r]);
      }
}

// ---------- launch ----------
extern "C" void kernel_launch(void* const* d_in, const int* in_sizes, int n_in,
                              void* d_out, int out_size, void* d_ws, size_t ws_size,
                              hipStream_t stream) {
  const float* x      = (const float*)d_in[0];
  const float* n1g    = (const float*)d_in[1];
  const float* n1b    = (const float*)d_in[2];
  const float* qkv_w  = (const float*)d_in[3];
  const float* qkv_b  = (const float*)d_in[4];
  const float* rpb    = (const float*)d_in[5];
  const float* proj_w = (const float*)d_in[6];
  const float* proj_b = (const float*)d_in[7];
  const float* n2g    = (const float*)d_in[8];
  const float* n2b    = (const float*)d_in[9];
  const float* fc1_w  = (const float*)d_in[10];
  const float* fc1_b  = (const float*)d_in[11];
  const float* fc2_w  = (const float*)d_in[12];
  const float* fc2_b  = (const float*)d_in[13];
  float* out = (float*)d_out;
  char* ws = (char*)d_ws;

  // workspace layout (bytes): weights_bf16 | attn_bias | lnbuf | [qkv | attn_out] / fc1_out
  u16*   wb    = (u16*)ws;                        // 1769472 el
  float* biasb = (float*)(ws + 3538944);          // 49152 f32
  u16*   lnbuf = (u16*)(ws + 3735552);            // 100352*384
  u16*   qkvb  = (u16*)(ws + 80805888);           // 100352*1152
  u16*   attnb = (u16*)(ws + 312016896);          // 100352*384
  u16*   fc1ob = (u16*)(ws + 80805888);           // 100352*1536 (aliases dead qkvb+attnb)

  const u16* qkv_wb  = wb;
  const u16* proj_wb = wb + 442368;
  const u16* fc1_wb  = wb + 589824;
  const u16* fc2_wb  = wb + 1179648;

  cvt_weights<<<6912, 256, 0, stream>>>(qkv_w, proj_w, fc1_w, fc2_w, wb);
  bias_kernel<<<192, 256, 0, stream>>>(rpb, biasb);
  ln_kernel<true><<<25088, 256, 0, stream>>>(x, n1g, n1b, lnbuf);
  gemm_bf16<0><<<dim3(784, 9), 256, 0, stream>>>(lnbuf, qkv_wb, qkv_b, 100352, 1152, 384, qkvb, nullptr, nullptr);
  attn_kernel<<<4704, 256, 0, stream>>>(qkvb, biasb, attnb);
  gemm_bf16<1><<<dim3(784, 3), 256, 0, stream>>>(attnb, proj_wb, proj_b, 100352, 384, 384, nullptr, out, x);
  ln_kernel<false><<<25088, 256, 0, stream>>>(out, n2g, n2b, lnbuf);
  gemm_bf16<2><<<dim3(784, 12), 256, 0, stream>>>(lnbuf, fc1_wb, fc1_b, 100352, 1536, 384, fc1ob, nullptr, nullptr);
  gemm_bf16<3><<<dim3(784, 3), 256, 0, stream>>>(fc1ob, fc2_wb, fc2_b, 100352, 384, 1536, nullptr, out, nullptr);
}

// Round 2
// 1216.410 us; speedup vs baseline: 1.7445x; 1.7445x over previous
//
#include <hip/hip_runtime.h>
#include <math.h>

typedef unsigned short u16;
typedef float v4f __attribute__((ext_vector_type(4)));
typedef short v8s __attribute__((ext_vector_type(8)));

// ---------- helpers ----------
__device__ __forceinline__ u16 f2bf(float f) {
  union { float f; unsigned u; } c; c.f = f;
  unsigned u = c.u;
  u += 0x7fff + ((u >> 16) & 1);   // RNE
  return (u16)(u >> 16);
}

// window-row r (win*64+n, shifted frame) -> natural token index.
__device__ __forceinline__ int row_to_token(int r) {
  int win = r >> 6, n = r & 63;
  int b = (win >= 784) ? 1 : 0;
  int wrem = win - b * 784;
  int wd = wrem / 196;
  int r2 = wrem - wd * 196;
  int wh = r2 / 14;
  int ww = r2 - wh * 14;
  int d = wd * 4 + (n >> 4);
  int h = wh * 4 + ((n >> 2) & 3);
  int w = ww * 4 + (n & 3);
  d = (d + 2) & 15;
  h += 2; if (h >= 56) h -= 56;
  w += 2; if (w >= 56) w -= 56;
  return ((b * 16 + d) * 56 + h) * 56 + w;
}

__device__ __forceinline__ int region_label(int n, int bd, int bh, int bw) {
  int ld = bd ? (((n >> 4) >= 2) ? 2 : 1) : 0;
  int lh = bh ? ((((n >> 2) & 3) >= 2) ? 2 : 1) : 0;
  int lw = bw ? (((n & 3) >= 2) ? 2 : 1) : 0;
  return ld * 9 + lh * 3 + lw;
}

// ---------- weight transpose + bf16 convert: src f32 [K][N] -> dst bf16 [N][K] ----------
__global__ __launch_bounds__(256) void transpose_w(const float* __restrict__ src, u16* __restrict__ dst,
                                                   int K, int N) {
  __shared__ u16 t[32][33];
  int kt = blockIdx.x * 32, nt = blockIdx.y * 32;
  int lx = threadIdx.x & 31, ly = threadIdx.x >> 5;   // 8 rows/pass
#pragma unroll
  for (int i = 0; i < 32; i += 8)
    t[ly + i][lx] = f2bf(src[(size_t)(kt + ly + i) * N + nt + lx]);
  __syncthreads();
#pragma unroll
  for (int i = 0; i < 32; i += 8)
    dst[(size_t)(nt + ly + i) * K + kt + lx] = t[lx][ly + i];
}

__global__ __launch_bounds__(256) void bias_kernel(const float* __restrict__ rpb, float* __restrict__ biasb) {
  int i = blockIdx.x * 256 + threadIdx.x;   // 49152 = 12*64*64, layout [h][n][m]
  int h = i >> 12, n = (i >> 6) & 63, m = i & 63;
  int dd = (n >> 4) - (m >> 4) + 3;
  int dh = ((n >> 2) & 3) - ((m >> 2) & 3) + 3;
  int dw = (n & 3) - (m & 3) + 3;
  biasb[i] = rpb[(dd * 49 + dh * 7 + dw) * 12 + h];
}

// ---------- LayerNorm (one wave per token row) ----------
template<bool MAP>
__global__ __launch_bounds__(256) void ln_kernel(const float* __restrict__ x, const float* __restrict__ g,
                                                 const float* __restrict__ bta, u16* __restrict__ out) {
  int wid = threadIdx.x >> 6, lane = threadIdx.x & 63;
  int r = blockIdx.x * 4 + wid;
  int t = MAP ? row_to_token(r) : r;
  const float* src = x + (size_t)t * 384;
  float v[6]; float s = 0.f;
#pragma unroll
  for (int i = 0; i < 6; i++) { v[i] = src[lane + i * 64]; s += v[i]; }
#pragma unroll
  for (int off = 1; off < 64; off <<= 1) s += __shfl_xor(s, off);
  float mu = s * (1.f / 384.f);
  float vs = 0.f;
#pragma unroll
  for (int i = 0; i < 6; i++) { float d = v[i] - mu; vs += d * d; }
#pragma unroll
  for (int off = 1; off < 64; off <<= 1) vs += __shfl_xor(vs, off);
  float rstd = 1.f / sqrtf(vs * (1.f / 384.f) + 1e-5f);
  u16* dst = out + (size_t)r * 384;
#pragma unroll
  for (int i = 0; i < 6; i++) {
    int c = lane + i * 64;
    dst[c] = f2bf((v[i] - mu) * rstd * g[c] + bta[c]);
  }
}

// ---------- GEMM: 128x128 tile, BK=32, 4 waves, 16x16x32 bf16 MFMA ----------
// A: [M][K] bf16.  Bw: [N][K] bf16 (pre-transposed).  blockIdx.x = N-tile.
// EPI: 0=qkv(bias->bf16)  1=proj(bias + scatter + shortcut -> f32 d_out)
//      2=fc1(bias+gelu->bf16)  3=fc2(bias, += d_out f32)
template<int EPI>
__global__ __launch_bounds__(256) void gemm_bf16(const u16* __restrict__ A, const u16* __restrict__ Bw,
                                                 const float* __restrict__ bias, int M, int N, int K,
                                                 u16* __restrict__ out_bf, float* __restrict__ out_f,
                                                 const float* __restrict__ resid) {
  __shared__ u16 As[128][40];   // [m][k], +8 pad
  __shared__ u16 Bs[128][40];   // [n][k], +8 pad
  const int tid = threadIdx.x;
  const int n0 = blockIdx.x * 128;
  const int m0 = blockIdx.y * 128;
  const int wid = tid >> 6, lane = tid & 63;
  const int wm = (wid >> 1) * 64, wn = (wid & 1) * 64;
  const int l15 = lane & 15, q4 = lane >> 4;
  v4f acc[4][4];
#pragma unroll
  for (int i = 0; i < 4; i++)
#pragma unroll
    for (int j = 0; j < 4; j++) acc[i][j] = (v4f){0.f, 0.f, 0.f, 0.f};

  const int srow = tid >> 2, skc = (tid & 3) * 8;

  for (int k0 = 0; k0 < K; k0 += 32) {
#pragma unroll
    for (int i = 0; i < 2; i++) {           // A tile 128x32
      int r = srow + i * 64;
      float4 ld = *(const float4*)(A + (size_t)(m0 + r) * K + k0 + skc);
      *(float4*)&As[r][skc] = ld;
    }
#pragma unroll
    for (int i = 0; i < 2; i++) {           // B tile 128x32 (same layout as A)
      int r = srow + i * 64;
      float4 ld = *(const float4*)(Bw + (size_t)(n0 + r) * K + k0 + skc);
      *(float4*)&Bs[r][skc] = ld;
    }
    __syncthreads();
    v8s afr[4], bfr[4];
#pragma unroll
    for (int tm = 0; tm < 4; tm++) afr[tm] = *(const v8s*)&As[wm + tm * 16 + l15][q4 * 8];
#pragma unroll
    for (int tn = 0; tn < 4; tn++) bfr[tn] = *(const v8s*)&Bs[wn + tn * 16 + l15][q4 * 8];
#pragma unroll
    for (int tm = 0; tm < 4; tm++)
#pragma unroll
      for (int tn = 0; tn < 4; tn++)
        acc[tm][tn] = __builtin_amdgcn_mfma_f32_16x16x32_bf16(afr[tm], bfr[tn], acc[tm][tn], 0, 0, 0);
    __syncthreads();
  }

#pragma unroll
  for (int tm = 0; tm < 4; tm++) {
#pragma unroll
    for (int tn = 0; tn < 4; tn++) {
      const int gcol = n0 + wn + tn * 16 + l15;
      const float bb = bias[gcol];
#pragma unroll
      for (int r = 0; r < 4; r++) {
        const int grow = m0 + wm + tm * 16 + q4 * 4 + r;
        float val = acc[tm][tn][r] + bb;
        if constexpr (EPI == 0) {
          out_bf[(size_t)grow * N + gcol] = f2bf(val);
        } else if constexpr (EPI == 2) {
          val = 0.5f * val * (1.f + erff(val * 0.70710678118654752f));
          out_bf[(size_t)grow * N + gcol] = f2bf(val);
        } else if constexpr (EPI == 1) {
          int t_ = row_to_token(grow);
          out_f[(size_t)t_ * 384 + gcol] = resid[(size_t)t_ * 384 + gcol] + val;
        } else {
          out_f[(size_t)grow * 384 + gcol] += val;
        }
      }
    }
  }
}

// ---------- attention: one wave per (window, head) ----------
__global__ __launch_bounds__(256) void attn_kernel(const u16* __restrict__ qkv, const float* __restrict__ biasb,
                                                   u16* __restrict__ outb) {
  __shared__ u16 P[4][64][72];              // per-wave P tile, bf16, padded
  int wid = threadIdx.x >> 6, lane = threadIdx.x & 63;
  int g = blockIdx.x * 4 + wid;
  int win = g / 12, head = g - win * 12;
  int l15 = lane & 15, q4 = lane >> 4;
  const u16* base = qkv + (size_t)win * 64 * 1152;
  const u16* qp = base + head * 32;
  const u16* kp = base + 384 + head * 32;
  const u16* vp = base + 768 + head * 32;

  v8s a[4], kb[4];
#pragma unroll
  for (int tm = 0; tm < 4; tm++) a[tm] = *(const v8s*)(qp + (size_t)(tm * 16 + l15) * 1152 + q4 * 8);
#pragma unroll
  for (int tn = 0; tn < 4; tn++) kb[tn] = *(const v8s*)(kp + (size_t)(tn * 16 + l15) * 1152 + q4 * 8);
  v4f acc[4][4];
#pragma unroll
  for (int i = 0; i < 4; i++)
#pragma unroll
    for (int j = 0; j < 4; j++) acc[i][j] = (v4f){0.f, 0.f, 0.f, 0.f};
#pragma unroll
  for (int tm = 0; tm < 4; tm++)
#pragma unroll
    for (int tn = 0; tn < 4; tn++)
      acc[tm][tn] = __builtin_amdgcn_mfma_f32_16x16x32_bf16(a[tm], kb[tn], acc[tm][tn], 0, 0, 0);

  int wrem = win % 784;
  int wd = wrem / 196, r2 = wrem % 196, wh = r2 / 14, ww = r2 % 14;
  int bd = (wd == 3), bh = (wh == 13), bw = (ww == 13);
  const float* bptr = biasb + head * 4096;
  int mlab[4];
#pragma unroll
  for (int tn = 0; tn < 4; tn++) mlab[tn] = region_label(tn * 16 + l15, bd, bh, bw);

#pragma unroll
  for (int tm = 0; tm < 4; tm++) {
#pragma unroll
    for (int r = 0; r < 4; r++) {
      int n = tm * 16 + q4 * 4 + r;
      int nlab = region_label(n, bd, bh, bw);
      float sv[4];
      float mx = -1e30f;
#pragma unroll
      for (int tn = 0; tn < 4; tn++) {
        int m = tn * 16 + l15;
        float s = acc[tm][tn][r] * 0.17677669529663687f + bptr[n * 64 + m];
        if (mlab[tn] != nlab) s -= 100.f;
        sv[tn] = s;
        mx = fmaxf(mx, s);
      }
#pragma unroll
      for (int off = 1; off < 16; off <<= 1) mx = fmaxf(mx, __shfl_xor(mx, off));
      float sum = 0.f;
#pragma unroll
      for (int tn = 0; tn < 4; tn++) { float e = __expf(sv[tn] - mx); sv[tn] = e; sum += e; }
#pragma unroll
      for (int off = 1; off < 16; off <<= 1) sum += __shfl_xor(sum, off);
      float inv = 1.f / sum;
#pragma unroll
      for (int tn = 0; tn < 4; tn++) P[wid][n][tn * 16 + l15] = f2bf(sv[tn] * inv);
    }
  }
  __syncthreads();   // C-layout -> A-layout via LDS

  v4f o[4][2];
#pragma unroll
  for (int i = 0; i < 4; i++) { o[i][0] = (v4f){0.f,0.f,0.f,0.f}; o[i][1] = (v4f){0.f,0.f,0.f,0.f}; }
#pragma unroll
  for (int kt = 0; kt < 2; kt++) {
    v8s pa[4];
#pragma unroll
    for (int tm = 0; tm < 4; tm++) pa[tm] = *(const v8s*)&P[wid][tm * 16 + l15][kt * 32 + q4 * 8];
#pragma unroll
    for (int tn = 0; tn < 2; tn++) {
      v8s vb;
#pragma unroll
      for (int j = 0; j < 8; j++) vb[j] = (short)vp[(size_t)(kt * 32 + q4 * 8 + j) * 1152 + tn * 16 + l15];
#pragma unroll
      for (int tm = 0; tm < 4; tm++)
        o[tm][tn] = __builtin_amdgcn_mfma_f32_16x16x32_bf16(pa[tm], vb, o[tm][tn], 0, 0, 0);
    }
  }
#pragma unroll
  for (int tm = 0; tm < 4; tm++)
#pragma unroll
    for (int tn = 0; tn < 2; tn++)
#pragma unroll
      for (int r = 0; r < 4; r++) {
        int n = tm * 16 + q4 * 4 + r;
        outb[(size_t)(win * 64 + n) * 384 + head * 32 + tn * 16 + l15] = f2bf(o[tm][tn][r]);
      }
}

// ---------- launch ----------
extern "C" void kernel_launch(void* const* d_in, const int* in_sizes, int n_in,
                              void* d_out, int out_size, void* d_ws, size_t ws_size,
                              hipStream_t stream) {
  const float* x      = (const float*)d_in[0];
  const float* n1g    = (const float*)d_in[1];
  const float* n1b    = (const float*)d_in[2];
  const float* qkv_w  = (const float*)d_in[3];
  const float* qkv_b  = (const float*)d_in[4];
  const float* rpb    = (const float*)d_in[5];
  const float* proj_w = (const float*)d_in[6];
  const float* proj_b = (const float*)d_in[7];
  const float* n2g    = (const float*)d_in[8];
  const float* n2b    = (const float*)d_in[9];
  const float* fc1_w  = (const float*)d_in[10];
  const float* fc1_b  = (const float*)d_in[11];
  const float* fc2_w  = (const float*)d_in[12];
  const float* fc2_b  = (const float*)d_in[13];
  float* out = (float*)d_out;
  char* ws = (char*)d_ws;

  // workspace layout (bytes): weights_bf16(T) | attn_bias | lnbuf | [qkv | attn_out] / fc1_out
  u16*   wb    = (u16*)ws;                        // 1769472 el
  float* biasb = (float*)(ws + 3538944);          // 49152 f32
  u16*   lnbuf = (u16*)(ws + 3735552);            // 100352*384
  u16*   qkvb  = (u16*)(ws + 80805888);           // 100352*1152
  u16*   attnb = (u16*)(ws + 312016896);          // 100352*384
  u16*   fc1ob = (u16*)(ws + 80805888);           // 100352*1536 (aliases dead qkvb+attnb)

  u16* qkv_wt  = wb;                  // [1152][384]
  u16* proj_wt = wb + 442368;         // [384][384]
  u16* fc1_wt  = wb + 589824;         // [1536][384]
  u16* fc2_wt  = wb + 1179648;        // [384][1536]

  transpose_w<<<dim3(12, 36), 256, 0, stream>>>(qkv_w,  qkv_wt,  384, 1152);
  transpose_w<<<dim3(12, 12), 256, 0, stream>>>(proj_w, proj_wt, 384, 384);
  transpose_w<<<dim3(12, 48), 256, 0, stream>>>(fc1_w,  fc1_wt,  384, 1536);
  transpose_w<<<dim3(48, 12), 256, 0, stream>>>(fc2_w,  fc2_wt,  1536, 384);
  bias_kernel<<<192, 256, 0, stream>>>(rpb, biasb);
  ln_kernel<true><<<25088, 256, 0, stream>>>(x, n1g, n1b, lnbuf);
  gemm_bf16<0><<<dim3(9, 784), 256, 0, stream>>>(lnbuf, qkv_wt, qkv_b, 100352, 1152, 384, qkvb, nullptr, nullptr);
  attn_kernel<<<4704, 256, 0, stream>>>(qkvb, biasb, attnb);
  gemm_bf16<1><<<dim3(3, 784), 256, 0, stream>>>(attnb, proj_wt, proj_b, 100352, 384, 384, nullptr, out, x);
  ln_kernel<false><<<25088, 256, 0, stream>>>(out, n2g, n2b, lnbuf);
  gemm_bf16<2><<<dim3(12, 784), 256, 0, stream>>>(lnbuf, fc1_wt, fc1_b, 100352, 1536, 384, fc1ob, nullptr, nullptr);
  gemm_bf16<3><<<dim3(3, 784), 256, 0, stream>>>(fc1ob, fc2_wt, fc2_b, 100352, 384, 1536, nullptr, out, nullptr);
}